// Round 2
// baseline (582.895 us; speedup 1.0000x reference)
//
#include <hip/hip_runtime.h>

#define NT 512            // threads per block (8 waves)
#define NPOS 1024         // positions (tree leaves) per batch
#define CH 8              // channels

struct WPtrs {
  const float* W[10];
  const float* Bv[10];
};

// Bank-spread hash on 16B-chunk index: fold ALL high bits into the 3
// bank-group bits. Bijective (only low 3 bits change).
__device__ __forceinline__ int swz(int ci) {
  return ci ^ (((ci >> 3) ^ (ci >> 6) ^ (ci >> 9)) & 7);
}

__global__ __launch_bounds__(NT, 4) void butterfly_kernel(
    const float* __restrict__ x,
    const float* __restrict__ F,      // in_filter [16][1][8]
    const float* __restrict__ fbias,  // [8]
    WPtrs P,
    const float* __restrict__ fea,    // [1024][8][16]
    float* __restrict__ out)
{
  // state: 1024 rows x 8ch fp32 = 2048 float4 chunks. Ping-pong = 64 KB
  // -> 2 blocks/CU (16 waves/CU).
  __shared__ float4 sA[2048];
  __shared__ float4 sB[2048];

  const int tid = threadIdx.x;
  const int b = blockIdx.x;

  // ---------------- phase 1: input conv (kernel=16, stride=16) ----------------
  float Fw[128];
  {
    const float4* F4 = (const float4*)F;
#pragma unroll
    for (int i = 0; i < 32; ++i) {
      float4 v = F4[i];
      Fw[4*i+0] = v.x; Fw[4*i+1] = v.y; Fw[4*i+2] = v.z; Fw[4*i+3] = v.w;
    }
  }
  float ib[8];
  {
    const float4* B4 = (const float4*)fbias;
    float4 v0 = B4[0], v1 = B4[1];
    ib[0]=v0.x; ib[1]=v0.y; ib[2]=v0.z; ib[3]=v0.w;
    ib[4]=v1.x; ib[5]=v1.y; ib[6]=v1.z; ib[7]=v1.w;
  }
#pragma unroll
  for (int i = 0; i < NPOS / NT; ++i) {   // 2 iterations
    int n = tid + i * NT;
    const float4* xb = (const float4*)(x + ((size_t)b) * 16384 + n * 16);
    float xin[16];
#pragma unroll
    for (int q = 0; q < 4; ++q) {
      float4 v = xb[q];
      xin[4*q+0] = v.x; xin[4*q+1] = v.y; xin[4*q+2] = v.z; xin[4*q+3] = v.w;
    }
    float acc[8];
#pragma unroll
    for (int c = 0; c < 8; ++c) acc[c] = ib[c];
#pragma unroll
    for (int f = 0; f < 16; ++f) {
#pragma unroll
      for (int c = 0; c < 8; ++c) acc[c] += xin[f] * Fw[f * 8 + c];
    }
    sA[swz(2*n)]   = make_float4(fmaxf(acc[0],0.f), fmaxf(acc[1],0.f), fmaxf(acc[2],0.f), fmaxf(acc[3],0.f));
    sA[swz(2*n+1)] = make_float4(fmaxf(acc[4],0.f), fmaxf(acc[5],0.f), fmaxf(acc[6],0.f), fmaxf(acc[7],0.f));
  }
  __syncthreads();

  // ---------------- phase 2: 10 butterfly levels ----------------
  // Flat layout p = t*K + k. Child row r = t*K + k reads parents at
  // q0 = t*K + (k>>1), q1 = q0 + K/2 (t-major block locality).
  float4* src = sA;
  float4* dst = sB;
  for (int lvl = 0; lvl < 10; ++lvl) {
    const int K = 2 << lvl;
    const int T = NPOS / K;
    const float* Wl = P.W[lvl];   // [K][2][8][8]
    const float* Bl = P.Bv[lvl];  // [K][8]

    int kFirst, kStep, tFirst, tStep;
    if (K >= NT) { kFirst = tid; kStep = NT; tFirst = 0; tStep = 1; }
    else {
      int tpp = NT / K;                 // threads sharing one branch k (tpp = T/2 < T)
      kFirst = tid / tpp; kStep = K;    // single k iteration
      tFirst = tid - kFirst * tpp; tStep = tpp;
    }
    for (int k = kFirst; k < K; k += kStep) {
      float w[128];
      {
        const float4* W4 = (const float4*)(Wl + k * 128);
#pragma unroll
        for (int i2 = 0; i2 < 32; ++i2) {
          float4 v = W4[i2];
          w[4*i2+0] = v.x; w[4*i2+1] = v.y; w[4*i2+2] = v.z; w[4*i2+3] = v.w;
        }
      }
      float bk[8];
      {
        const float4* B4 = (const float4*)(Bl + k * 8);
        float4 v0 = B4[0], v1 = B4[1];
        bk[0]=v0.x; bk[1]=v0.y; bk[2]=v0.z; bk[3]=v0.w;
        bk[4]=v1.x; bk[5]=v1.y; bk[6]=v1.z; bk[7]=v1.w;
      }
      const int kp = k >> 1;
      for (int t = tFirst; t < T; t += tStep) {
        int q0 = t * K + kp;
        int q1 = q0 + (K >> 1);
        float4 a0 = src[swz(2*q0)], a1 = src[swz(2*q0 + 1)];
        float4 c0 = src[swz(2*q1)], c1 = src[swz(2*q1 + 1)];
        float pa[8] = {a0.x,a0.y,a0.z,a0.w,a1.x,a1.y,a1.z,a1.w};
        float pb[8] = {c0.x,c0.y,c0.z,c0.w,c1.x,c1.y,c1.z,c1.w};
        float acc[8];
#pragma unroll
        for (int d = 0; d < 8; ++d) acc[d] = bk[d];
#pragma unroll
        for (int c = 0; c < 8; ++c) {
#pragma unroll
          for (int d = 0; d < 8; ++d)
            acc[d] += pa[c] * w[c * 8 + d] + pb[c] * w[64 + c * 8 + d];
        }
        int r = t * K + k;
        dst[swz(2*r)]   = make_float4(fmaxf(acc[0],0.f), fmaxf(acc[1],0.f), fmaxf(acc[2],0.f), fmaxf(acc[3],0.f));
        dst[swz(2*r+1)] = make_float4(fmaxf(acc[4],0.f), fmaxf(acc[5],0.f), fmaxf(acc[6],0.f), fmaxf(acc[7],0.f));
      }
    }
    __syncthreads();
    float4* tmp = src; src = dst; dst = tmp;
  }

  // ---------------- phase 3: per-branch dense [8 -> 16], float4-wide ----------------
  // out[b, k*16 + f4*4 .. +3] = sum_c state[k][c] * fea[k][c][f4*4 .. +3]
  const float4* fea4 = (const float4*)fea;   // [k][c][f4] -> k*32 + c*4 + f4
  float4* out4 = (float4*)(out + ((size_t)b) * 16384);
#pragma unroll 1
  for (int i = 0; i < 4096 / NT; ++i) {   // 8 iterations over (k, f4)
    int item = tid + i * NT;
    int k = item >> 2, f4 = item & 3;
    float4 s0 = src[swz(2*k)];
    float4 s1 = src[swz(2*k + 1)];
    float sc[8] = {s0.x,s0.y,s0.z,s0.w,s1.x,s1.y,s1.z,s1.w};
    float4 acc = make_float4(0.f, 0.f, 0.f, 0.f);
#pragma unroll
    for (int c = 0; c < 8; ++c) {
      float4 fv = fea4[k * 32 + c * 4 + f4];
      acc.x += sc[c] * fv.x;
      acc.y += sc[c] * fv.y;
      acc.z += sc[c] * fv.z;
      acc.w += sc[c] * fv.w;
    }
    out4[k * 4 + f4] = acc;
  }
}

extern "C" void kernel_launch(void* const* d_in, const int* in_sizes, int n_in,
                              void* d_out, int out_size, void* d_ws, size_t ws_size,
                              hipStream_t stream) {
  const float* x  = (const float*)d_in[0];
  const float* F  = (const float*)d_in[1];
  const float* fb = (const float*)d_in[2];
  WPtrs P;
  for (int l = 0; l < 10; ++l) {
    P.W[l]  = (const float*)d_in[3 + 2 * l];
    P.Bv[l] = (const float*)d_in[4 + 2 * l];
  }
  const float* fea = (const float*)d_in[23];
  float* out = (float*)d_out;
  dim3 grid(1024), block(NT);
  butterfly_kernel<<<grid, block, 0, stream>>>(x, F, fb, P, fea, out);
}

// Round 3
// 242.860 us; speedup vs baseline: 2.4001x; 2.4001x over previous
//
#include <hip/hip_runtime.h>

#define NT 512            // threads per block (8 waves)
#define NPOS 1024         // positions (tree leaves) per batch
#define CH 8              // channels

struct WPtrs {
  const float* W[10];
  const float* Bv[10];
};

// Bank-spread hash on 16B-chunk index: fold ALL high bits into the 3
// bank-group bits. Bijective (only low 3 bits change).
__device__ __forceinline__ int swz(int ci) {
  return ci ^ (((ci >> 3) ^ (ci >> 6) ^ (ci >> 9)) & 7);
}

// launch_bounds arg2=2: empirically (R1 vs R2) this is blocks/CU —
// arg 4 capped VGPR at 64 and spilled (1.2 GB scratch writes, 3.5x slower).
// arg 2 -> 128-VGPR cap, kernel needs ~116, and LDS (64 KB) caps us at
// 2 blocks/CU anyway, which 116 VGPRs exactly permits.
__global__ __launch_bounds__(NT, 2) void butterfly_kernel(
    const float* __restrict__ x,
    const float* __restrict__ F,      // in_filter [16][1][8]
    const float* __restrict__ fbias,  // [8]
    WPtrs P,
    const float* __restrict__ fea,    // [1024][8][16]
    float* __restrict__ out)
{
  // state: 1024 rows x 8ch fp32 = 2048 float4 chunks. Ping-pong = 64 KB
  // -> 2 blocks/CU (16 waves/CU).
  __shared__ float4 sA[2048];
  __shared__ float4 sB[2048];

  const int tid = threadIdx.x;
  const int b = blockIdx.x;

  // ---------------- phase 1: input conv (kernel=16, stride=16) ----------------
  float Fw[128];
  {
    const float4* F4 = (const float4*)F;
#pragma unroll
    for (int i = 0; i < 32; ++i) {
      float4 v = F4[i];
      Fw[4*i+0] = v.x; Fw[4*i+1] = v.y; Fw[4*i+2] = v.z; Fw[4*i+3] = v.w;
    }
  }
  float ib[8];
  {
    const float4* B4 = (const float4*)fbias;
    float4 v0 = B4[0], v1 = B4[1];
    ib[0]=v0.x; ib[1]=v0.y; ib[2]=v0.z; ib[3]=v0.w;
    ib[4]=v1.x; ib[5]=v1.y; ib[6]=v1.z; ib[7]=v1.w;
  }
#pragma unroll
  for (int i = 0; i < NPOS / NT; ++i) {   // 2 iterations
    int n = tid + i * NT;
    const float4* xb = (const float4*)(x + ((size_t)b) * 16384 + n * 16);
    float xin[16];
#pragma unroll
    for (int q = 0; q < 4; ++q) {
      float4 v = xb[q];
      xin[4*q+0] = v.x; xin[4*q+1] = v.y; xin[4*q+2] = v.z; xin[4*q+3] = v.w;
    }
    float acc[8];
#pragma unroll
    for (int c = 0; c < 8; ++c) acc[c] = ib[c];
#pragma unroll
    for (int f = 0; f < 16; ++f) {
#pragma unroll
      for (int c = 0; c < 8; ++c) acc[c] += xin[f] * Fw[f * 8 + c];
    }
    sA[swz(2*n)]   = make_float4(fmaxf(acc[0],0.f), fmaxf(acc[1],0.f), fmaxf(acc[2],0.f), fmaxf(acc[3],0.f));
    sA[swz(2*n+1)] = make_float4(fmaxf(acc[4],0.f), fmaxf(acc[5],0.f), fmaxf(acc[6],0.f), fmaxf(acc[7],0.f));
  }
  __syncthreads();

  // ---------------- phase 2: 10 butterfly levels ----------------
  // Flat layout p = t*K + k. Child row r = t*K + k reads parents at
  // q0 = t*K + (k>>1), q1 = q0 + K/2 (t-major block locality).
  float4* src = sA;
  float4* dst = sB;
  for (int lvl = 0; lvl < 10; ++lvl) {
    const int K = 2 << lvl;
    const int T = NPOS / K;
    const float* Wl = P.W[lvl];   // [K][2][8][8]
    const float* Bl = P.Bv[lvl];  // [K][8]

    int kFirst, kStep, tFirst, tStep;
    if (K >= NT) { kFirst = tid; kStep = NT; tFirst = 0; tStep = 1; }
    else {
      int tpp = NT / K;                 // threads sharing one branch k
      kFirst = tid / tpp; kStep = K;    // single k iteration
      tFirst = tid - kFirst * tpp; tStep = tpp;
    }
    for (int k = kFirst; k < K; k += kStep) {
      float w[128];
      {
        const float4* W4 = (const float4*)(Wl + k * 128);
#pragma unroll
        for (int i2 = 0; i2 < 32; ++i2) {
          float4 v = W4[i2];
          w[4*i2+0] = v.x; w[4*i2+1] = v.y; w[4*i2+2] = v.z; w[4*i2+3] = v.w;
        }
      }
      float bk[8];
      {
        const float4* B4 = (const float4*)(Bl + k * 8);
        float4 v0 = B4[0], v1 = B4[1];
        bk[0]=v0.x; bk[1]=v0.y; bk[2]=v0.z; bk[3]=v0.w;
        bk[4]=v1.x; bk[5]=v1.y; bk[6]=v1.z; bk[7]=v1.w;
      }
      const int kp = k >> 1;
      for (int t = tFirst; t < T; t += tStep) {
        int q0 = t * K + kp;
        int q1 = q0 + (K >> 1);
        float4 a0 = src[swz(2*q0)], a1 = src[swz(2*q0 + 1)];
        float4 c0 = src[swz(2*q1)], c1 = src[swz(2*q1 + 1)];
        float pa[8] = {a0.x,a0.y,a0.z,a0.w,a1.x,a1.y,a1.z,a1.w};
        float pb[8] = {c0.x,c0.y,c0.z,c0.w,c1.x,c1.y,c1.z,c1.w};
        float acc[8];
#pragma unroll
        for (int d = 0; d < 8; ++d) acc[d] = bk[d];
#pragma unroll
        for (int c = 0; c < 8; ++c) {
#pragma unroll
          for (int d = 0; d < 8; ++d)
            acc[d] += pa[c] * w[c * 8 + d] + pb[c] * w[64 + c * 8 + d];
        }
        int r = t * K + k;
        dst[swz(2*r)]   = make_float4(fmaxf(acc[0],0.f), fmaxf(acc[1],0.f), fmaxf(acc[2],0.f), fmaxf(acc[3],0.f));
        dst[swz(2*r+1)] = make_float4(fmaxf(acc[4],0.f), fmaxf(acc[5],0.f), fmaxf(acc[6],0.f), fmaxf(acc[7],0.f));
      }
    }
    __syncthreads();
    float4* tmp = src; src = dst; dst = tmp;
  }

  // ---------------- phase 3: per-branch dense [8 -> 16], float4-wide ----------------
  // out[b, k*16 + f4*4 .. +3] = sum_c state[k][c] * fea[k][c][f4*4 .. +3]
  const float4* fea4 = (const float4*)fea;   // [k][c][f4] -> k*32 + c*4 + f4
  float4* out4 = (float4*)(out + ((size_t)b) * 16384);
#pragma unroll 1
  for (int i = 0; i < 4096 / NT; ++i) {   // 8 iterations over (k, f4)
    int item = tid + i * NT;
    int k = item >> 2, f4 = item & 3;
    float4 s0 = src[swz(2*k)];
    float4 s1 = src[swz(2*k + 1)];
    float sc[8] = {s0.x,s0.y,s0.z,s0.w,s1.x,s1.y,s1.z,s1.w};
    float4 acc = make_float4(0.f, 0.f, 0.f, 0.f);
#pragma unroll
    for (int c = 0; c < 8; ++c) {
      float4 fv = fea4[k * 32 + c * 4 + f4];
      acc.x += sc[c] * fv.x;
      acc.y += sc[c] * fv.y;
      acc.z += sc[c] * fv.z;
      acc.w += sc[c] * fv.w;
    }
    out4[k * 4 + f4] = acc;
  }
}

extern "C" void kernel_launch(void* const* d_in, const int* in_sizes, int n_in,
                              void* d_out, int out_size, void* d_ws, size_t ws_size,
                              hipStream_t stream) {
  const float* x  = (const float*)d_in[0];
  const float* F  = (const float*)d_in[1];
  const float* fb = (const float*)d_in[2];
  WPtrs P;
  for (int l = 0; l < 10; ++l) {
    P.W[l]  = (const float*)d_in[3 + 2 * l];
    P.Bv[l] = (const float*)d_in[4 + 2 * l];
  }
  const float* fea = (const float*)d_in[23];
  float* out = (float*)d_out;
  dim3 grid(1024), block(NT);
  butterfly_kernel<<<grid, block, 0, stream>>>(x, F, fb, P, fea, out);
}

// Round 4
// 120.723 us; speedup vs baseline: 4.8284x; 2.0117x over previous
//
#include <hip/hip_runtime.h>

#define NT1 512
#define NT2 256

struct WPtrs { const float* W[7]; const float* Bv[7]; };

// K1 state swizzle on 16B-chunk index (proven in R2/R3: conflicts 1.57e7 -> 1.3e6)
__device__ __forceinline__ int swz(int ci) {
  return ci ^ (((ci >> 3) ^ (ci >> 6) ^ (ci >> 9)) & 7);
}
// K2 state swizzle: layout [b][16 chunks]; fold batch bits into bank-group bits
__device__ __forceinline__ int scr(int ci) { return ci ^ ((ci >> 4) & 7); }

// ---------------- K1: input conv + levels 1..7 ----------------
// Each thread owns 2 output channels (dq = channel-pair): w2[16] = 32 regs,
// targeting <=85 VGPR (launch_bounds (512,3) -> cap 2048/(3*8) = 85).
__global__ __launch_bounds__(NT1, 3) void bfly_k1(
    const float* __restrict__ x, const float* __restrict__ F,
    const float* __restrict__ fbias, WPtrs P, float* __restrict__ ws)
{
  __shared__ float4 sA[2048];
  __shared__ float4 sB[2048];
  const int tid = threadIdx.x;
  const int b = blockIdx.x;
  const int dq  = tid & 3;        // channel-pair 0..3 (d = 2dq, 2dq+1)
  const int g   = tid >> 2;       // 128 work groups
  const int sub = (dq & 1) * 8;   // byte offset within 16B chunk
  const int cof = dq >> 1;        // chunk offset within 32B row

  // phase 1: input conv (kernel=16, stride=16), d-split
  {
    float2 fw[16];
#pragma unroll
    for (int f = 0; f < 16; ++f) fw[f] = *(const float2*)(F + f * 8 + dq * 2);
    float2 bias = *(const float2*)(fbias + dq * 2);
    const float* xb = x + (size_t)b * 16384;
#pragma unroll 1
    for (int i = 0; i < 8; ++i) {
      int n = g + i * 128;
      const float4* xr = (const float4*)(xb + n * 16);
      float xin[16];
#pragma unroll
      for (int q = 0; q < 4; ++q) {
        float4 v = xr[q];
        xin[4*q]=v.x; xin[4*q+1]=v.y; xin[4*q+2]=v.z; xin[4*q+3]=v.w;
      }
      float ax = bias.x, ay = bias.y;
#pragma unroll
      for (int f = 0; f < 16; ++f) { ax += xin[f]*fw[f].x; ay += xin[f]*fw[f].y; }
      ax = fmaxf(ax, 0.f); ay = fmaxf(ay, 0.f);
      *(float2*)((char*)sA + swz(2*n + cof)*16 + sub) = make_float2(ax, ay);
    }
  }
  __syncthreads();

  // levels 1..7: flat row p = t*K + k; child (k,t) reads parents
  // p0 = 2t*Kp + (k>>1), p1 = p0 + Kp.
  float4* src = sA; float4* dst = sB;
#pragma unroll 1
  for (int lvl = 1; lvl <= 7; ++lvl) {
    const int K = 1 << lvl, Kp = K >> 1, G = 128 >> lvl;
    const int k = g & (K - 1), tIdx = g >> lvl;
    const float* Wl = P.W[lvl-1];
    float2 w2[16];                       // [s*8+c] -> W[k][s][c][2dq..2dq+1]
#pragma unroll
    for (int s = 0; s < 2; ++s)
#pragma unroll
      for (int c = 0; c < 8; ++c)
        w2[s*8+c] = *(const float2*)(Wl + k*128 + s*64 + c*8 + dq*2);
    float2 bias = *(const float2*)(P.Bv[lvl-1] + k*8 + dq*2);
    const int kp = k >> 1;
#pragma unroll 1
    for (int i = 0; i < 8; ++i) {
      int t = tIdx + i * G;
      int p0 = 2*t*Kp + kp, p1 = p0 + Kp;
      float4 A0 = src[swz(2*p0)], A1 = src[swz(2*p0+1)];
      float4 C0 = src[swz(2*p1)], C1 = src[swz(2*p1+1)];
      float pa[8] = {A0.x,A0.y,A0.z,A0.w,A1.x,A1.y,A1.z,A1.w};
      float pb[8] = {C0.x,C0.y,C0.z,C0.w,C1.x,C1.y,C1.z,C1.w};
      float ax = bias.x, ay = bias.y;
#pragma unroll
      for (int c = 0; c < 8; ++c) {
        ax += pa[c]*w2[c].x + pb[c]*w2[8+c].x;
        ay += pa[c]*w2[c].y + pb[c]*w2[8+c].y;
      }
      ax = fmaxf(ax, 0.f); ay = fmaxf(ay, 0.f);
      int r = t*K + k;
      *(float2*)((char*)dst + swz(2*r + cof)*16 + sub) = make_float2(ax, ay);
    }
    __syncthreads();
    float4* tmp = src; src = dst; dst = tmp;
  }

  // copy level-7 state to ws as [j][b][t7][c] (j = level-7 branch = row % 128)
#pragma unroll 1
  for (int o = tid; o < 2048; o += NT1) {
    int j = o >> 4, t = (o >> 1) & 7, h = o & 1;
    float4 v = src[swz(2*(t*128 + j) + h)];
    *(float4*)(ws + (size_t)j*65536 + b*64 + t*8 + h*4) = v;
  }
}

// ---------------- K2: levels 8..10 + dense, weight-stationary ----------------
// block = (j, 32-batch tile). All of j's subtree weights staged in LDS once.
__global__ __launch_bounds__(NT2, 6) void bfly_k2(
    const float* __restrict__ ws,
    const float* __restrict__ W8, const float* __restrict__ B8,
    const float* __restrict__ W9, const float* __restrict__ B9,
    const float* __restrict__ W10, const float* __restrict__ B10,
    const float* __restrict__ fea, float* __restrict__ out)
{
  __shared__ float4 sA[512], sB[512];    // 32 batches x 16 chunks, ping-pong
  __shared__ float swt[2928];            // W8|W9|W10|B8|B9|B10|FEA
  const int tid = threadIdx.x;
  const int j = blockIdx.x, b0 = blockIdx.y * 32;
  const int dq = tid & 3, g = tid >> 2;  // 64 groups
  const int sub = (dq & 1) * 8, cof = dq >> 1;

  // stage level-7 state (8KB contiguous)
  {
    const float4* s4 = (const float4*)(ws + (size_t)j*65536 + (size_t)b0*64);
#pragma unroll
    for (int it = 0; it < 2; ++it) {
      int idx = tid + it*256;            // b_l*16 + chunk
      sA[scr(idx)] = s4[idx];
    }
  }
  // stage weights (contiguous f4 blocks)
  {
    float4* d = (float4*)swt;
    for (int i = tid; i < 64;  i += NT2) d[i]       = ((const float4*)(W8  + j*256 ))[i];
    for (int i = tid; i < 128; i += NT2) d[64+i]    = ((const float4*)(W9  + j*512 ))[i];
    for (int i = tid; i < 256; i += NT2) d[192+i]   = ((const float4*)(W10 + j*1024))[i];
    if (tid < 4)  d[448+tid] = ((const float4*)(B8  + j*16))[tid];
    if (tid < 8)  d[452+tid] = ((const float4*)(B9  + j*32))[tid];
    if (tid < 16) d[460+tid] = ((const float4*)(B10 + j*64))[tid];
    for (int i = tid; i < 256; i += NT2) d[476+i]   = ((const float4*)(fea + j*1024))[i];
  }
  __syncthreads();

  auto loadW = [&](int woff, int boff, int k_l, float2* w2, float2& bias) {
#pragma unroll
    for (int s = 0; s < 2; ++s)
#pragma unroll
      for (int c = 0; c < 8; ++c)
        w2[s*8+c] = *(const float2*)(swt + woff + k_l*128 + s*64 + c*8 + dq*2);
    bias = *(const float2*)(swt + boff + k_l*8 + dq*2);
  };
  auto doItem = [&](const float4* S, float4* D, const float2* w2, float2 bias,
                    int k_l, int bl, int t, int KL, int KPL) {
    int p0 = 2*t*KPL + (k_l >> 1), p1 = p0 + KPL;
    int base = bl * 16;
    float4 A0 = S[scr(base + 2*p0)], A1 = S[scr(base + 2*p0 + 1)];
    float4 C0 = S[scr(base + 2*p1)], C1 = S[scr(base + 2*p1 + 1)];
    float pa[8] = {A0.x,A0.y,A0.z,A0.w,A1.x,A1.y,A1.z,A1.w};
    float pb[8] = {C0.x,C0.y,C0.z,C0.w,C1.x,C1.y,C1.z,C1.w};
    float ax = bias.x, ay = bias.y;
#pragma unroll
    for (int c = 0; c < 8; ++c) {
      ax += pa[c]*w2[c].x + pb[c]*w2[8+c].x;
      ay += pa[c]*w2[c].y + pb[c]*w2[8+c].y;
    }
    ax = fmaxf(ax, 0.f); ay = fmaxf(ay, 0.f);
    int r = t*KL + k_l;
    *(float2*)((char*)D + scr(base + 2*r + cof)*16 + sub) = make_float2(ax, ay);
  };

  { // level 8: sA(v7) -> sB ; local K=2, Kp=1
    int k_l = g & 1, bl = g >> 1;
    float2 w2[16], bias; loadW(0, 1792, k_l, w2, bias);
#pragma unroll
    for (int t = 0; t < 4; ++t) doItem(sA, sB, w2, bias, k_l, bl, t, 2, 1);
  }
  __syncthreads();
  { // level 9: sB -> sA ; K=4, Kp=2
    int k_l = g & 3, bq = g >> 2;
    float2 w2[16], bias; loadW(256, 1808, k_l, w2, bias);
#pragma unroll
    for (int it = 0; it < 4; ++it)
      doItem(sB, sA, w2, bias, k_l, bq + (it>>1)*16, it & 1, 4, 2);
  }
  __syncthreads();
  { // level 10: sA -> sB ; K=8, Kp=4
    int k_l = g & 7, bo = g >> 3;
    float2 w2[16], bias; loadW(768, 1840, k_l, w2, bias);
#pragma unroll
    for (int it = 0; it < 4; ++it)
      doItem(sA, sB, w2, bias, k_l, bo + it*8, 0, 8, 4);
  }
  __syncthreads();
  { // dense: out[b, (8j+k)*16+f] = sum_c v10[k][c] * fea[8j+k][c][f]
    int ch = tid & 7, b_l = tid >> 3;    // 8 chunks x 32 batches
    float* op = out + ((size_t)(b0 + b_l)) * 16384 + j * 128;
#pragma unroll
    for (int it = 0; it < 4; ++it) {
      int cc = ch + it*8, k = cc >> 2, fq = cc & 3;
      float4 s0 = sB[scr(b_l*16 + k*2)];
      float4 s1 = sB[scr(b_l*16 + k*2 + 1)];
      float sc[8] = {s0.x,s0.y,s0.z,s0.w,s1.x,s1.y,s1.z,s1.w};
      float4 acc = make_float4(0.f, 0.f, 0.f, 0.f);
#pragma unroll
      for (int c = 0; c < 8; ++c) {
        float4 fv = *(const float4*)(swt + 1904 + k*128 + c*16 + fq*4);
        acc.x += sc[c]*fv.x; acc.y += sc[c]*fv.y;
        acc.z += sc[c]*fv.z; acc.w += sc[c]*fv.w;
      }
      *(float4*)(op + k*16 + fq*4) = acc;
    }
  }
}

extern "C" void kernel_launch(void* const* d_in, const int* in_sizes, int n_in,
                              void* d_out, int out_size, void* d_ws, size_t ws_size,
                              hipStream_t stream) {
  const float* x  = (const float*)d_in[0];
  const float* F  = (const float*)d_in[1];
  const float* fb = (const float*)d_in[2];
  WPtrs P;
  for (int l = 0; l < 7; ++l) {
    P.W[l]  = (const float*)d_in[3 + 2 * l];
    P.Bv[l] = (const float*)d_in[4 + 2 * l];
  }
  const float* W8  = (const float*)d_in[17];
  const float* B8  = (const float*)d_in[18];
  const float* W9  = (const float*)d_in[19];
  const float* B9  = (const float*)d_in[20];
  const float* W10 = (const float*)d_in[21];
  const float* B10 = (const float*)d_in[22];
  const float* fea = (const float*)d_in[23];
  float* ws = (float*)d_ws;   // 128*1024*64 floats = 33.5 MB
  float* out = (float*)d_out;

  bfly_k1<<<dim3(1024), dim3(NT1), 0, stream>>>(x, F, fb, P, ws);
  bfly_k2<<<dim3(128, 32), dim3(NT2), 0, stream>>>(ws, W8, B8, W9, B9, W10, B10, fea, out);
}